// Round 3
// baseline (1018.179 us; speedup 1.0000x reference)
//
#include <hip/hip_runtime.h>
#include <math.h>
#include <stdint.h>

#define DD 768
#define NT 256
#define DE 6144

typedef _Float16 half8 __attribute__((ext_vector_type(8)));
typedef _Float16 half4 __attribute__((ext_vector_type(4)));
typedef short short8 __attribute__((ext_vector_type(8)));
typedef float floatx4 __attribute__((ext_vector_type(4)));

__device__ __forceinline__ void async_ld16(const void* g, void* l) {
  __builtin_amdgcn_global_load_lds(
      (const __attribute__((address_space(1))) unsigned int*)g,
      (__attribute__((address_space(3))) unsigned int*)l, 16, 0, 0);
}

// ---------------------------------------------------------------------------
// Prep A: WT[d][k] = (f16)W[k][d], XOR-swizzled within each 64-f16 chunk:
// 16B-group g of row d lives at group g^(d&7), so lane-contiguous
// global_load_lds lands a bank-balanced image in LDS.
// ---------------------------------------------------------------------------
__global__ __launch_bounds__(256) void transpose_cvt(
    const float* __restrict__ Wn, const float* __restrict__ Wg,
    _Float16* __restrict__ WnT, _Float16* __restrict__ WgT)
{
  const float* W = blockIdx.z ? Wg : Wn;
  _Float16* WT = blockIdx.z ? WgT : WnT;
  __shared__ float tile[32][33];
  const int tx = threadIdx.x & 31, ty = threadIdx.x >> 5;
  const int d0 = blockIdx.x * 32, k0 = blockIdx.y * 32;
  #pragma unroll
  for (int p = 0; p < 4; ++p)
    tile[ty + p*8][tx] = W[(size_t)(k0 + ty + p*8)*DD + d0 + tx];
  __syncthreads();
  #pragma unroll
  for (int p = 0; p < 4; ++p) {
    const int d = d0 + ty + p*8;
    const int k = k0 + tx;
    const int idx = d*DD + (k & ~63) + ((((k >> 3) & 7) ^ (d & 7)) << 3) + (k & 7);
    WT[idx] = (_Float16)tile[tx][ty + p*8];
  }
}

// ---------------------------------------------------------------------------
// Prep B: fp16 copies of the embeddings (A-operand source for score_mfma).
// ---------------------------------------------------------------------------
__global__ __launch_bounds__(256) void cvt_lr(
    const float* __restrict__ L, const float* __restrict__ R,
    _Float16* __restrict__ Lh, _Float16* __restrict__ Rh)
{
  const float* src = blockIdx.y ? R : L;
  _Float16* dst = blockIdx.y ? Rh : Lh;
  const int o = blockIdx.x*1024 + threadIdx.x*4;
  float4 v = *(const float4*)&src[o];
  half4 h; h[0] = (_Float16)v.x; h[1] = (_Float16)v.y;
  h[2] = (_Float16)v.z; h[3] = (_Float16)v.w;
  *(half4*)&dst[o] = h;
}

// ---------------------------------------------------------------------------
// Stage 1 v4: A-OPERAND DIRECT FROM GLOBAL (no A in LDS at all).
// R2 post-mortem: kernel was LDS-BW-bound (384KB read + 96KB write per
// K-step per CU ~ 110us of the 223us). Fix: the MFMA A-fragment layout
// (lane=(m,q) -> row m, k-chunk q*8) maps to 16x64B contiguous global
// segments per load, so each wave builds |Lh-Rh| fragments directly in
// registers from L2-resident Rh (same f16 sub + bit-abs -> bit-identical),
// prefetched for step t+1 during step t's MFMA cluster. B stays LDS-staged
// (4-way j-reuse) but frags are read ONCE per K-step (register-cached).
// LDS traffic 480KB -> 160KB per K-step; LDS 128KB -> 64KB; one barrier
// per K-step. Per-acc-element MFMA order (k ascending) unchanged -> Sp
// bit-identical -> argmax identical.
// ---------------------------------------------------------------------------
__global__ __launch_bounds__(512, 2) void score_mfma(
    const _Float16* __restrict__ Lh, const _Float16* __restrict__ Rh,
    const _Float16* __restrict__ WnT, const _Float16* __restrict__ WgT,
    const float* __restrict__ bn, const float* __restrict__ bg,
    const float* __restrict__ Wl, float* __restrict__ Sp)
{
  const int dbase = blockIdx.x * 128;   // 6 d-blocks
  const int i     = blockIdx.y;         // 256 i
  const int tid   = threadIdx.x;

  __shared__ _Float16 Bns[2][128*64];   // 2 x 16 KB
  __shared__ _Float16 Bgs[2][128*64];   // 2 x 16 KB

  floatx4 accn[4][4] = {};
  floatx4 accg[4][4] = {};

  const int lane = tid & 63;
  const int wid  = tid >> 6;            // 0..7
  const int wj = (wid & 3) * 64;        // 4 waves across j (tile j = full 256)
  const int wd = (wid >> 2) * 64;       // 2 waves across d
  const int m = lane & 15;
  const int q = lane >> 4;
  const int gq8 = ((q ^ (m & 7)) << 3); // swizzled fragment k-offset base

  const int drow = lane >> 3;   // DMA: 8 rows/inst
  const int dseg = lane & 7;

  int brow[4];
  #pragma unroll
  for (int t4 = 0; t4 < 4; ++t4) brow[t4] = (wd + t4*16 + m) * 64;

  // A-fragment global sources: row (wj + t4*16 + m), k-chunk q*8.
  // Lanes q=0..3 of one row cover one contiguous 64B line.
  const _Float16* arow[4];
  #pragma unroll
  for (int t4 = 0; t4 < 4; ++t4)
    arow[t4] = Rh + (size_t)(wj + t4*16 + m)*DD + q*8;
  const _Float16* lrow = Lh + (size_t)i*DD + q*8;

  auto stageB = [&](int k0, int c) {
    #pragma unroll
    for (int tt = 0; tt < 2; ++tt) {
      const int brow0 = wid*16 + tt*8;
      async_ld16(&WnT[(size_t)(dbase + brow0 + drow)*DD + k0 + dseg*8],
                 &Bns[c][brow0*64]);
      async_ld16(&WgT[(size_t)(dbase + brow0 + drow)*DD + k0 + dseg*8],
                 &Bgs[c][brow0*64]);
    }
  };

  auto loadA = [&](int k0, half8 (&rv)[4][2], half8 (&lh)[2]) {
    #pragma unroll
    for (int kki = 0; kki < 2; ++kki)
      lh[kki] = *(const half8*)&lrow[k0 + kki*32];
    #pragma unroll
    for (int t4 = 0; t4 < 4; ++t4)
      #pragma unroll
      for (int kki = 0; kki < 2; ++kki)
        rv[t4][kki] = *(const half8*)&arow[t4][k0 + kki*32];
  };

  auto cvtA = [&](half8 (&rv)[4][2], half8 (&lh)[2], half8 (&af)[4][2]) {
    #pragma unroll
    for (int t4 = 0; t4 < 4; ++t4)
      #pragma unroll
      for (int kki = 0; kki < 2; ++kki) {
        half8 dv8 = lh[kki] - rv[t4][kki];
        short8 sb; __builtin_memcpy(&sb, &dv8, 16);
        sb &= (short)0x7FFF;
        __builtin_memcpy(&af[t4][kki], &sb, 16);
      }
  };

  half8 afA[4][2], afB[4][2];

  // One K-step: consume afc + B buf c; prefetch (DMA B + load A) for t+1.
  auto kstep = [&](int t, int c, half8 (&afc)[4][2], half8 (&afn)[4][2]) {
    const bool st = (t < 11);
    const int k0n = (t + 1) * 64;
    half8 rvn[4][2], lhn[2];
    if (st) {
      stageB(k0n, c ^ 1);     // DMA into the buffer freed at last barrier
      loadA(k0n, rvn, lhn);   // A prefetch: latency hides under MFMA cluster
    }
    __builtin_amdgcn_sched_barrier(0);  // pin prefetch issue before cluster
    __builtin_amdgcn_s_setprio(1);
    #pragma unroll
    for (int td = 0; td < 4; ++td) {
      half8 bn_[2], bg_[2];
      #pragma unroll
      for (int kki = 0; kki < 2; ++kki) {
        const int ko = (kki*32) ^ gq8;
        bn_[kki] = *(const half8*)&Bns[c][brow[td] + ko];
        bg_[kki] = *(const half8*)&Bgs[c][brow[td] + ko];
      }
      #pragma unroll
      for (int kki = 0; kki < 2; ++kki)
        #pragma unroll
        for (int tj = 0; tj < 4; ++tj) {
          accn[tj][td] = __builtin_amdgcn_mfma_f32_16x16x32_f16(
              afc[tj][kki], bn_[kki], accn[tj][td], 0, 0, 0);
          accg[tj][td] = __builtin_amdgcn_mfma_f32_16x16x32_f16(
              afc[tj][kki], bg_[kki], accg[tj][td], 0, 0, 0);
        }
    }
    __builtin_amdgcn_s_setprio(0);
    if (st) cvtA(rvn, lhn, afn);   // waits on rvn loads (issued pre-cluster)
    __builtin_amdgcn_sched_barrier(0);
    __syncthreads();               // drains DMA(t+1); frees buf c for t+2
  };

  // ---- prologue: stage B(0) + build A(0) in registers
  stageB(0, 0);
  {
    half8 rv0[4][2], lh0[2];
    loadA(0, rv0, lh0);
    cvtA(rv0, lh0, afA);
  }
  __syncthreads();

  // ---- main loop: 12 K-steps, ping-pong A register buffers (static idx)
  for (int t = 0; t < 12; t += 2) {
    kstep(t,     0, afA, afB);
    kstep(t + 1, 1, afB, afA);
  }

  // ---- epilogue: highway + Wl contraction; C layout col=lane&15, row=q*4+r
  float bnv[4], bgv[4], wlv[4], lv[4];
  int dv[4];
  #pragma unroll
  for (int td = 0; td < 4; ++td) {
    const int d = dbase + wd + td*16 + m;
    dv[td] = d; bnv[td] = bn[d]; bgv[td] = bg[d]; wlv[td] = Wl[d];
    lv[td] = (float)Lh[i*DD + d];
  }
  const int jb = wj;
  const int plane = blockIdx.x * 2 + (wid >> 2);   // 12 planes
  float* Sout = Sp + (size_t)plane * NT * NT + (size_t)i * NT;
  #pragma unroll
  for (int tj = 0; tj < 4; ++tj) {
    #pragma unroll
    for (int r = 0; r < 4; ++r) {
      const int j = jb + tj*16 + q*4 + r;
      float sc = 0.f;
      #pragma unroll
      for (int td = 0; td < 4; ++td) {
        const float nv = accn[tj][td][r] + bnv[td];
        const float gp = accg[tj][td][r] + bgv[td];
        const float g  = 1.f / (1.f + __expf(-gp));
        const float c  = fabsf(lv[td] - (float)Rh[(size_t)j*DD + dv[td]]);
        sc += (fmaxf(nv, 0.f)*g + (1.f - g)*c) * wlv[td];
      }
      sc += __shfl_xor(sc, 1, 16);
      sc += __shfl_xor(sc, 2, 16);
      sc += __shfl_xor(sc, 4, 16);
      sc += __shfl_xor(sc, 8, 16);
      if (m == 0) Sout[j] = sc;
    }
  }
}

// ---------------------------------------------------------------------------
// Stage 2 (fused): blocks 0..511 -> argmax over rows/cols of sum-of-planes S;
// blocks 512/513 -> per-token attribute scores + segment softmax weights.
// ---------------------------------------------------------------------------
__global__ __launch_bounds__(256) void argmax_attr(
    const float* __restrict__ Sp,
    int* __restrict__ idxL, int* __restrict__ idxR,
    const float* __restrict__ Lemb, const float* __restrict__ Remb,
    const float* __restrict__ AEl, const float* __restrict__ AEr,
    const int* __restrict__ lensL, const int* __restrict__ lensR,
    float* __restrict__ wS, int* __restrict__ segA)
{
  const int b = blockIdx.x;
  const int t = threadIdx.x;

  if (b < 2*NT) {
    // ---- argmax path
    const size_t off = (b < NT) ? ((size_t)b*NT + t) : ((size_t)t*NT + (b - NT));
    float v = 0.f;
    #pragma unroll
    for (int p = 0; p < 12; ++p) v += Sp[(size_t)p*NT*NT + off];
    int idx = t;
    #pragma unroll
    for (int mm = 1; mm < 64; mm <<= 1) {
      float ov = __shfl_xor(v, mm, 64);
      int   oi = __shfl_xor(idx, mm, 64);
      if (ov > v || (ov == v && oi < idx)) { v = ov; idx = oi; }
    }
    __shared__ float sv[4]; __shared__ int si[4];
    if ((t & 63) == 0) { sv[t>>6] = v; si[t>>6] = idx; }
    __syncthreads();
    if (t == 0) {
      #pragma unroll
      for (int w = 1; w < 4; ++w)
        if (sv[w] > v || (sv[w] == v && si[w] < idx)) { v = sv[w]; idx = si[w]; }
      if (b < NT) idxL[b] = idx; else idxR[b - NT] = idx;
    }
    return;
  }

  // ---- attr_score path (b = 512 -> left, 513 -> right)
  const int side = b - 2*NT;
  const float* tok = side ? Remb : Lemb;
  const float* AE  = side ? AEr  : AEl;
  const int* lens  = side ? lensR : lensL;
  const int c0 = lens[0], c1 = c0 + lens[1], c2 = c1 + lens[2];
  const int seg = (t < c0) ? 0 : (t < c1) ? 1 : (t < c2) ? 2 : 3;
  float s = 0.f;
  const float4* tr = (const float4*)&tok[(size_t)t*DD];
  const float4* ar = (const float4*)&AE[(size_t)seg*DD];
  for (int k = 0; k < DD/4; ++k) {
    float4 a = tr[k], bb = ar[k];
    s += a.x*bb.x + a.y*bb.y + a.z*bb.z + a.w*bb.w;
  }
  __shared__ float scS[NT]; __shared__ int segS[NT];
  __shared__ float mS[4], zS[4];
  scS[t] = s; segS[t] = seg;
  __syncthreads();
  if (t < 4) {
    float mx = -INFINITY;
    for (int u = 0; u < NT; ++u) if (segS[u] == t) mx = fmaxf(mx, scS[u]);
    mS[t] = mx;
    float z = 0.f;
    for (int u = 0; u < NT; ++u) if (segS[u] == t) z += __expf(scS[u] - mx);
    zS[t] = z;
  }
  __syncthreads();
  wS[side*NT + t] = __expf(s - mS[seg]) / zS[seg];
  segA[side*NT + t] = seg;
}

// ---------------------------------------------------------------------------
// Stage 3: weighted segment reduction of cmp rows, d-parallel (2x12 blocks).
// cmp recomputed in EXACT fp32 from the original embeddings.
// ---------------------------------------------------------------------------
__global__ __launch_bounds__(256) void attr_reduce(
    const float* __restrict__ Lemb, const float* __restrict__ Remb,
    const int* __restrict__ lensL, const int* __restrict__ lensR,
    const int* __restrict__ idxL, const int* __restrict__ idxR,
    const float* __restrict__ wS, const int* __restrict__ segA,
    const float* __restrict__ empty, float* __restrict__ x)
{
  const int side = blockIdx.x;
  const float* tok = side ? Remb : Lemb;
  const float* oth = side ? Lemb : Remb;
  const int* lens  = side ? lensR : lensL;
  const int* idx   = side ? idxR  : idxL;
  const float* w   = wS + side*NT;
  const int* sg    = segA + side*NT;
  float* xo = x + side*4*DD;
  const int t = threadIdx.x;
  const int dl = t & 63, uq = t >> 6;
  const int d = blockIdx.y*64 + dl;
  float a0 = 0.f, a1 = 0.f, a2 = 0.f, a3 = 0.f;
  for (int u = uq*64; u < uq*64 + 64; ++u) {
    const float c = fabsf(tok[(size_t)u*DD + d] - oth[(size_t)idx[u]*DD + d]);
    const float wc = w[u] * c;
    const int s = sg[u];
    a0 += (s == 0) ? wc : 0.f;
    a1 += (s == 1) ? wc : 0.f;
    a2 += (s == 2) ? wc : 0.f;
    a3 += (s == 3) ? wc : 0.f;
  }
  __shared__ float red[4][4][64];
  red[uq][0][dl] = a0; red[uq][1][dl] = a1;
  red[uq][2][dl] = a2; red[uq][3][dl] = a3;
  __syncthreads();
  if (uq == 0) {
    #pragma unroll
    for (int s = 0; s < 4; ++s) {
      float v = red[0][s][dl] + red[1][s][dl] + red[2][s][dl] + red[3][s][dl];
      xo[s*DD + d] = (lens[s] > 0) ? v : empty[d];
    }
  }
}

// ---------------------------------------------------------------------------
// Stage 4a: entity matvecs, float4 streaming, k-split into partials.
// grid (6 col-blocks, 64 k-blocks, 2 matrices) = 768 blocks. HBM-bound.
// ---------------------------------------------------------------------------
__global__ __launch_bounds__(256) void ent_matvec4(
    const float* __restrict__ x,
    const float* __restrict__ Wn, const float* __restrict__ Wg,
    float* __restrict__ pn, float* __restrict__ pg)
{
  const float* W = blockIdx.z ? Wg : Wn;
  float* p = blockIdx.z ? pg : pn;
  __shared__ float xs[96];
  const int db = blockIdx.x;
  const int kb = blockIdx.y;
  const int tid = threadIdx.x;
  if (tid < 96) xs[tid] = x[kb*96 + tid];
  __syncthreads();
  const int col = db*1024 + tid*4;
  float4 a = {0.f,0.f,0.f,0.f};
  const size_t base = (size_t)kb*96*DE + col;
  #pragma unroll 8
  for (int kk = 0; kk < 96; ++kk) {
    const float xv = xs[kk];
    float4 w = *(const float4*)&W[base + (size_t)kk*DE];
    a.x = fmaf(xv, w.x, a.x); a.y = fmaf(xv, w.y, a.y);
    a.z = fmaf(xv, w.z, a.z); a.w = fmaf(xv, w.w, a.w);
  }
  *(float4*)&p[(size_t)kb*DE + col] = a;
}

__global__ __launch_bounds__(256) void ent_reduce(
    const float* __restrict__ pn, const float* __restrict__ pg,
    float* __restrict__ yn, float* __restrict__ yg)
{
  const int o = blockIdx.x*256 + threadIdx.x;
  float sn = 0.f, sg = 0.f;
  for (int kb = 0; kb < 64; ++kb) {
    sn += pn[(size_t)kb*DE + o];
    sg += pg[(size_t)kb*DE + o];
  }
  yn[o] = sn; yg[o] = sg;
}

// ---------------------------------------------------------------------------
// Stage 4b: entity highway + logits + softmax -> out[2].
// ---------------------------------------------------------------------------
__global__ __launch_bounds__(256) void final_kernel(
    const float* __restrict__ x, const float* __restrict__ yn,
    const float* __restrict__ yg, const float* __restrict__ bn,
    const float* __restrict__ bg, const float* __restrict__ Wl,
    const float* __restrict__ bl, float* __restrict__ out)
{
  const int tid = threadIdx.x;
  float a0 = 0.f, a1 = 0.f;
  for (int p = 0; p < DE/256; ++p) {
    int d = p*256 + tid;
    float n  = yn[d] + bn[d];
    float gp = yg[d] + bg[d];
    float h  = fmaxf(n, 0.f);
    float g  = 1.f / (1.f + __expf(-gp));
    float hw = h*g + (1.f - g)*x[d];
    a0 += hw * Wl[d*2 + 0];
    a1 += hw * Wl[d*2 + 1];
  }
  #pragma unroll
  for (int mm = 1; mm < 64; mm <<= 1) {
    a0 += __shfl_xor(a0, mm, 64);
    a1 += __shfl_xor(a1, mm, 64);
  }
  __shared__ float s0[4], s1[4];
  if ((tid & 63) == 0) { s0[tid>>6] = a0; s1[tid>>6] = a1; }
  __syncthreads();
  if (tid == 0) {
    for (int w = 1; w < 4; ++w) { a0 += s0[w]; a1 += s1[w]; }
    float l0 = a0 + bl[0], l1 = a1 + bl[1];
    float m = fmaxf(l0, l1);
    float e0 = __expf(l0 - m), e1 = __expf(l1 - m);
    out[0] = e0 / (e0 + e1);
    out[1] = e1 / (e0 + e1);
  }
}

// ---------------------------------------------------------------------------
extern "C" void kernel_launch(void* const* d_in, const int* in_sizes, int n_in,
                              void* d_out, int out_size, void* d_ws, size_t ws_size,
                              hipStream_t stream) {
  const float* Lemb   = (const float*)d_in[0];
  const float* Remb   = (const float*)d_in[1];
  const float* Wn_tok = (const float*)d_in[2];
  const float* bn_tok = (const float*)d_in[3];
  const float* Wg_tok = (const float*)d_in[4];
  const float* bg_tok = (const float*)d_in[5];
  const float* Wl_tok = (const float*)d_in[6];
  // d_in[7] = b_lin_tok: constant shift, argmax-invariant -> unused
  const float* AEl    = (const float*)d_in[8];
  const float* AEr    = (const float*)d_in[9];
  const float* Wn_ent = (const float*)d_in[10];
  const float* bn_ent = (const float*)d_in[11];
  const float* Wg_ent = (const float*)d_in[12];
  const float* bg_ent = (const float*)d_in[13];
  const float* Wl_ent = (const float*)d_in[14];
  const float* bl_ent = (const float*)d_in[15];
  const float* empty  = (const float*)d_in[16];
  const int*   lensL  = (const int*)d_in[17];
  const int*   lensR  = (const int*)d_in[18];

  char* ws = (char*)d_ws;
  // Sp (12 planes, score stage) overlaps pn/pg (ent stage) -- disjoint in time.
  float* Sp   = (float*)(ws + 0);         // 12*65536 f = 3,145,728 B
  float* pn   = (float*)(ws + 0);         // 64*6144 f = 1,572,864 B
  float* pg   = (float*)(ws + 1572864);   // 64*6144 f
  int*  idxL  = (int*)  (ws + 3145728);   // 256
  int*  idxR  = (int*)  (ws + 3146752);   // 256
  float* x    = (float*)(ws + 3147776);   // 6144 f
  float* yn   = (float*)(ws + 3172352);   // 6144 f
  float* yg   = (float*)(ws + 3196928);   // 6144 f
  float* wSm  = (float*)(ws + 3221504);   // 512 f
  int*  segA  = (int*)  (ws + 3223552);   // 512
  _Float16* WnT = (_Float16*)(ws + 3225600);  // 768*768 f16 (swizzled)
  _Float16* WgT = (_Float16*)(ws + 4405248);  // 768*768 f16 (swizzled)
  _Float16* Lh  = (_Float16*)(ws + 5584896);  // 256*768 f16
  _Float16* Rh  = (_Float16*)(ws + 5978112);  // 256*768 f16

  transpose_cvt<<<dim3(24, 24, 2), 256, 0, stream>>>(Wn_tok, Wg_tok, WnT, WgT);
  cvt_lr<<<dim3(192, 2), 256, 0, stream>>>(Lemb, Remb, Lh, Rh);
  score_mfma<<<dim3(6, 256), 512, 0, stream>>>(
      Lh, Rh, WnT, WgT, bn_tok, bg_tok, Wl_tok, Sp);
  argmax_attr<<<514, 256, 0, stream>>>(
      Sp, idxL, idxR, Lemb, Remb, AEl, AEr, lensL, lensR, wSm, segA);
  attr_reduce<<<dim3(2, 12), 256, 0, stream>>>(
      Lemb, Remb, lensL, lensR, idxL, idxR, wSm, segA, empty, x);
  ent_matvec4<<<dim3(6, 64, 2), 256, 0, stream>>>(x, Wn_ent, Wg_ent, pn, pg);
  ent_reduce<<<24, 256, 0, stream>>>(pn, pg, yn, yg);
  final_kernel<<<1, 256, 0, stream>>>(
      x, yn, yg, bn_ent, bg_ent, Wl_ent, bl_ent, (float*)d_out);
}

// Round 4
// 959.417 us; speedup vs baseline: 1.0612x; 1.0612x over previous
//
#include <hip/hip_runtime.h>
#include <math.h>
#include <stdint.h>

#define DD 768
#define NT 256
#define DE 6144

typedef _Float16 half8 __attribute__((ext_vector_type(8)));
typedef _Float16 half4 __attribute__((ext_vector_type(4)));
typedef short short8 __attribute__((ext_vector_type(8)));
typedef float floatx4 __attribute__((ext_vector_type(4)));

__device__ __forceinline__ void async_ld16(const void* g, void* l) {
  __builtin_amdgcn_global_load_lds(
      (const __attribute__((address_space(1))) unsigned int*)g,
      (__attribute__((address_space(3))) unsigned int*)l, 16, 0, 0);
}

// ---------------------------------------------------------------------------
// Prep A: WT[d][k] = (f16)W[k][d], XOR-swizzled within each 64-f16 chunk:
// 16B-group g of row d lives at group g^(d&7), so lane-contiguous
// global_load_lds lands a bank-balanced image in LDS.
// ---------------------------------------------------------------------------
__global__ __launch_bounds__(256) void transpose_cvt(
    const float* __restrict__ Wn, const float* __restrict__ Wg,
    _Float16* __restrict__ WnT, _Float16* __restrict__ WgT)
{
  const float* W = blockIdx.z ? Wg : Wn;
  _Float16* WT = blockIdx.z ? WgT : WnT;
  __shared__ float tile[32][33];
  const int tx = threadIdx.x & 31, ty = threadIdx.x >> 5;
  const int d0 = blockIdx.x * 32, k0 = blockIdx.y * 32;
  #pragma unroll
  for (int p = 0; p < 4; ++p)
    tile[ty + p*8][tx] = W[(size_t)(k0 + ty + p*8)*DD + d0 + tx];
  __syncthreads();
  #pragma unroll
  for (int p = 0; p < 4; ++p) {
    const int d = d0 + ty + p*8;
    const int k = k0 + tx;
    const int idx = d*DD + (k & ~63) + ((((k >> 3) & 7) ^ (d & 7)) << 3) + (k & 7);
    WT[idx] = (_Float16)tile[tx][ty + p*8];
  }
}

// ---------------------------------------------------------------------------
// Prep B: fp16 copies of the embeddings (A-operand source for score_mfma).
// ---------------------------------------------------------------------------
__global__ __launch_bounds__(256) void cvt_lr(
    const float* __restrict__ L, const float* __restrict__ R,
    _Float16* __restrict__ Lh, _Float16* __restrict__ Rh)
{
  const float* src = blockIdx.y ? R : L;
  _Float16* dst = blockIdx.y ? Rh : Lh;
  const int o = blockIdx.x*1024 + threadIdx.x*4;
  float4 v = *(const float4*)&src[o];
  half4 h; h[0] = (_Float16)v.x; h[1] = (_Float16)v.y;
  h[2] = (_Float16)v.z; h[3] = (_Float16)v.w;
  *(half4*)&dst[o] = h;
}

// ---------------------------------------------------------------------------
// Stage 1 v5: A-in-registers (R3 idea) made to FIT the register file.
// R3 post-mortem: hipcc launch_bounds 2nd arg is CUDA-semantics (min
// BLOCKS/CU): (512,2) -> 16 waves/CU -> 128-VGPR cap -> accumulators
// spilled to scratch (1 GB WRITE_SIZE, 606us). Fix:
//   (a) __launch_bounds__(512,1) -> 256-VGPR cap (1 block/CU; LDS forces
//       that anyway).
//   (b) MATRIX-SPLIT waves: 8 waves = 2wj x 2wd x 2mat; each wave computes
//       ONE matrix (n or g) for its 64j x 64d tile -> acc 128->64 VGPR.
//       Peak live ~200 VGPR -> no spill. B-LDS reads per wave halve.
// A fragments (|Lh-Rh|) built directly in registers from L2-resident
// global (lane (m,q) -> row m, chunk q*8: 16x64B segments/load), double-
// buffered across K-steps; prefetch issued before the MFMA cluster.
// Epilogue: g-waves publish accg via padded LDS exchange (stride 68 f32,
// conflict-free b128), one barrier, n-waves run the highway math exactly
// as before -> same f32 bits -> Sp bit-identical -> argmax identical.
// ---------------------------------------------------------------------------
__global__ __launch_bounds__(512, 1) void score_mfma(
    const _Float16* __restrict__ Lh, const _Float16* __restrict__ Rh,
    const _Float16* __restrict__ WnT, const _Float16* __restrict__ WgT,
    const float* __restrict__ bn, const float* __restrict__ bg,
    const float* __restrict__ Wl, float* __restrict__ Sp)
{
  const int jbase = blockIdx.x * 128;   // 2 j-blocks
  const int dbase = blockIdx.y * 128;   // 6 d-blocks
  const int i     = blockIdx.z;         // 256 i
  const int tid   = threadIdx.x;

  __shared__ _Float16 Bns[2][128*64];   // 2 x 16 KB
  __shared__ _Float16 Bgs[2][128*64];   // 2 x 16 KB
  __shared__ float xchg[4][64*68];      // g->n acc exchange, 68-f32 pad rows

  floatx4 acc[4][4] = {};               // ONE matrix per wave

  const int lane = tid & 63;
  const int wid  = tid >> 6;                // 0..7
  const int mat  = wid >> 2;                // 0 = n-wave, 1 = g-wave
  const int wj   = (wid & 1) * 64;
  const int wd   = ((wid >> 1) & 1) * 64;
  const int reg  = wid & 3;                 // exchange region (wj,wd pair)
  const int m = lane & 15;
  const int q = lane >> 4;
  const int gq8 = ((q ^ (m & 7)) << 3);     // swizzled B k-offset base

  const int drow = lane >> 3;   // DMA: 8 rows/inst
  const int dseg = lane & 7;

  int brow[4];
  #pragma unroll
  for (int t4 = 0; t4 < 4; ++t4) brow[t4] = (wd + t4*16 + m) * 64;

  // A-fragment global sources: row (jbase + wj + t4*16 + m), chunk q*8.
  const _Float16* arow[4];
  #pragma unroll
  for (int t4 = 0; t4 < 4; ++t4)
    arow[t4] = Rh + (size_t)(jbase + wj + t4*16 + m)*DD + q*8;
  const _Float16* lrow = Lh + (size_t)i*DD + q*8;

  auto stageB = [&](int k0, int c) {
    #pragma unroll
    for (int tt = 0; tt < 2; ++tt) {
      const int brow0 = wid*16 + tt*8;
      async_ld16(&WnT[(size_t)(dbase + brow0 + drow)*DD + k0 + dseg*8],
                 &Bns[c][brow0*64]);
      async_ld16(&WgT[(size_t)(dbase + brow0 + drow)*DD + k0 + dseg*8],
                 &Bgs[c][brow0*64]);
    }
  };

  auto loadA = [&](int k0, half8 (&rv)[4][2], half8 (&lh)[2]) {
    #pragma unroll
    for (int kki = 0; kki < 2; ++kki)
      lh[kki] = *(const half8*)&lrow[k0 + kki*32];
    #pragma unroll
    for (int t4 = 0; t4 < 4; ++t4)
      #pragma unroll
      for (int kki = 0; kki < 2; ++kki)
        rv[t4][kki] = *(const half8*)&arow[t4][k0 + kki*32];
  };

  auto cvtA = [&](half8 (&rv)[4][2], half8 (&lh)[2], half8 (&af)[4][2]) {
    #pragma unroll
    for (int t4 = 0; t4 < 4; ++t4)
      #pragma unroll
      for (int kki = 0; kki < 2; ++kki) {
        half8 dv8 = lh[kki] - rv[t4][kki];
        short8 sb; __builtin_memcpy(&sb, &dv8, 16);
        sb &= (short)0x7FFF;
        __builtin_memcpy(&af[t4][kki], &sb, 16);
      }
  };

  half8 afA[4][2], afB[4][2];

  // One K-step: consume afc + B buf c; prefetch (DMA B + load A) for t+1.
  auto kstep = [&](int t, int c, half8 (&afc)[4][2], half8 (&afn)[4][2]) {
    const bool st = (t < 11);
    const int k0n = (t + 1) * 64;
    half8 rvn[4][2], lhn[2];
    if (st) {
      stageB(k0n, c ^ 1);     // DMA into the buffer freed at last barrier
      loadA(k0n, rvn, lhn);   // latency hides under the MFMA cluster
    }
    const _Float16* Bc = mat ? &Bgs[c][0] : &Bns[c][0];
    __builtin_amdgcn_sched_barrier(0);  // pin prefetch issue before cluster
    __builtin_amdgcn_s_setprio(1);
    #pragma unroll
    for (int td = 0; td < 4; ++td) {
      half8 bf[2];
      #pragma unroll
      for (int kki = 0; kki < 2; ++kki)
        bf[kki] = *(const half8*)&Bc[brow[td] + ((kki*32) ^ gq8)];
      #pragma unroll
      for (int kki = 0; kki < 2; ++kki)
        #pragma unroll
        for (int tj = 0; tj < 4; ++tj)
          acc[tj][td] = __builtin_amdgcn_mfma_f32_16x16x32_f16(
              afc[tj][kki], bf[kki], acc[tj][td], 0, 0, 0);
    }
    __builtin_amdgcn_s_setprio(0);
    if (st) cvtA(rvn, lhn, afn);   // consumes rvn (issued pre-cluster)
    __builtin_amdgcn_sched_barrier(0);
    __syncthreads();               // drains DMA(t+1); frees buf c for t+2
  };

  // ---- prologue: stage B(0) + build A(0) in registers
  stageB(0, 0);
  {
    half8 rv0[4][2], lh0[2];
    loadA(0, rv0, lh0);
    cvtA(rv0, lh0, afA);
  }
  __syncthreads();

  // ---- main loop: 12 K-steps, ping-pong A register buffers (static idx)
  for (int t = 0; t < 12; t += 2) {
    kstep(t,     0, afA, afB);
    kstep(t + 1, 1, afB, afA);
  }

  // ---- epilogue: g-waves publish accg; n-waves do highway + Wl + reduce.
  if (mat) {
    #pragma unroll
    for (int tj = 0; tj < 4; ++tj)
      #pragma unroll
      for (int td = 0; td < 4; ++td)
        *(floatx4*)&xchg[reg][(td*16 + m)*68 + tj*16 + q*4] = acc[tj][td];
  }
  __syncthreads();
  if (!mat) {
    float bnv[4], bgv[4], wlv[4], lv[4];
    int dv[4];
    #pragma unroll
    for (int td = 0; td < 4; ++td) {
      const int d = dbase + wd + td*16 + m;
      dv[td] = d; bnv[td] = bn[d]; bgv[td] = bg[d]; wlv[td] = Wl[d];
      lv[td] = (float)Lh[i*DD + d];
    }
    const int jb = jbase + wj;
    const int plane = blockIdx.y * 2 + (wd >> 6);   // 12 planes
    float* Sout = Sp + (size_t)plane * NT * NT + (size_t)i * NT;
    #pragma unroll
    for (int tj = 0; tj < 4; ++tj) {
      floatx4 ag[4];
      #pragma unroll
      for (int td = 0; td < 4; ++td)
        ag[td] = *(const floatx4*)&xchg[reg][(td*16 + m)*68 + tj*16 + q*4];
      #pragma unroll
      for (int r = 0; r < 4; ++r) {
        const int j = jb + tj*16 + q*4 + r;
        float sc = 0.f;
        #pragma unroll
        for (int td = 0; td < 4; ++td) {
          const float nv = acc[tj][td][r] + bnv[td];
          const float gp = ag[td][r] + bgv[td];
          const float g  = 1.f / (1.f + __expf(-gp));
          const float c  = fabsf(lv[td] - (float)Rh[(size_t)j*DD + dv[td]]);
          sc += (fmaxf(nv, 0.f)*g + (1.f - g)*c) * wlv[td];
        }
        sc += __shfl_xor(sc, 1, 16);
        sc += __shfl_xor(sc, 2, 16);
        sc += __shfl_xor(sc, 4, 16);
        sc += __shfl_xor(sc, 8, 16);
        if (m == 0) Sout[j] = sc;
      }
    }
  }
}

// ---------------------------------------------------------------------------
// Stage 2 (fused): blocks 0..511 -> argmax over rows/cols of sum-of-planes S;
// blocks 512/513 -> per-token attribute scores + segment softmax weights.
// ---------------------------------------------------------------------------
__global__ __launch_bounds__(256) void argmax_attr(
    const float* __restrict__ Sp,
    int* __restrict__ idxL, int* __restrict__ idxR,
    const float* __restrict__ Lemb, const float* __restrict__ Remb,
    const float* __restrict__ AEl, const float* __restrict__ AEr,
    const int* __restrict__ lensL, const int* __restrict__ lensR,
    float* __restrict__ wS, int* __restrict__ segA)
{
  const int b = blockIdx.x;
  const int t = threadIdx.x;

  if (b < 2*NT) {
    // ---- argmax path
    const size_t off = (b < NT) ? ((size_t)b*NT + t) : ((size_t)t*NT + (b - NT));
    float v = 0.f;
    #pragma unroll
    for (int p = 0; p < 12; ++p) v += Sp[(size_t)p*NT*NT + off];
    int idx = t;
    #pragma unroll
    for (int mm = 1; mm < 64; mm <<= 1) {
      float ov = __shfl_xor(v, mm, 64);
      int   oi = __shfl_xor(idx, mm, 64);
      if (ov > v || (ov == v && oi < idx)) { v = ov; idx = oi; }
    }
    __shared__ float sv[4]; __shared__ int si[4];
    if ((t & 63) == 0) { sv[t>>6] = v; si[t>>6] = idx; }
    __syncthreads();
    if (t == 0) {
      #pragma unroll
      for (int w = 1; w < 4; ++w)
        if (sv[w] > v || (sv[w] == v && si[w] < idx)) { v = sv[w]; idx = si[w]; }
      if (b < NT) idxL[b] = idx; else idxR[b - NT] = idx;
    }
    return;
  }

  // ---- attr_score path (b = 512 -> left, 513 -> right)
  const int side = b - 2*NT;
  const float* tok = side ? Remb : Lemb;
  const float* AE  = side ? AEr  : AEl;
  const int* lens  = side ? lensR : lensL;
  const int c0 = lens[0], c1 = c0 + lens[1], c2 = c1 + lens[2];
  const int seg = (t < c0) ? 0 : (t < c1) ? 1 : (t < c2) ? 2 : 3;
  float s = 0.f;
  const float4* tr = (const float4*)&tok[(size_t)t*DD];
  const float4* ar = (const float4*)&AE[(size_t)seg*DD];
  for (int k = 0; k < DD/4; ++k) {
    float4 a = tr[k], bb = ar[k];
    s += a.x*bb.x + a.y*bb.y + a.z*bb.z + a.w*bb.w;
  }
  __shared__ float scS[NT]; __shared__ int segS[NT];
  __shared__ float mS[4], zS[4];
  scS[t] = s; segS[t] = seg;
  __syncthreads();
  if (t < 4) {
    float mx = -INFINITY;
    for (int u = 0; u < NT; ++u) if (segS[u] == t) mx = fmaxf(mx, scS[u]);
    mS[t] = mx;
    float z = 0.f;
    for (int u = 0; u < NT; ++u) if (segS[u] == t) z += __expf(scS[u] - mx);
    zS[t] = z;
  }
  __syncthreads();
  wS[side*NT + t] = __expf(s - mS[seg]) / zS[seg];
  segA[side*NT + t] = seg;
}

// ---------------------------------------------------------------------------
// Stage 3: weighted segment reduction of cmp rows, d-parallel (2x12 blocks).
// cmp recomputed in EXACT fp32 from the original embeddings.
// ---------------------------------------------------------------------------
__global__ __launch_bounds__(256) void attr_reduce(
    const float* __restrict__ Lemb, const float* __restrict__ Remb,
    const int* __restrict__ lensL, const int* __restrict__ lensR,
    const int* __restrict__ idxL, const int* __restrict__ idxR,
    const float* __restrict__ wS, const int* __restrict__ segA,
    const float* __restrict__ empty, float* __restrict__ x)
{
  const int side = blockIdx.x;
  const float* tok = side ? Remb : Lemb;
  const float* oth = side ? Lemb : Remb;
  const int* lens  = side ? lensR : lensL;
  const int* idx   = side ? idxR  : idxL;
  const float* w   = wS + side*NT;
  const int* sg    = segA + side*NT;
  float* xo = x + side*4*DD;
  const int t = threadIdx.x;
  const int dl = t & 63, uq = t >> 6;
  const int d = blockIdx.y*64 + dl;
  float a0 = 0.f, a1 = 0.f, a2 = 0.f, a3 = 0.f;
  for (int u = uq*64; u < uq*64 + 64; ++u) {
    const float c = fabsf(tok[(size_t)u*DD + d] - oth[(size_t)idx[u]*DD + d]);
    const float wc = w[u] * c;
    const int s = sg[u];
    a0 += (s == 0) ? wc : 0.f;
    a1 += (s == 1) ? wc : 0.f;
    a2 += (s == 2) ? wc : 0.f;
    a3 += (s == 3) ? wc : 0.f;
  }
  __shared__ float red[4][4][64];
  red[uq][0][dl] = a0; red[uq][1][dl] = a1;
  red[uq][2][dl] = a2; red[uq][3][dl] = a3;
  __syncthreads();
  if (uq == 0) {
    #pragma unroll
    for (int s = 0; s < 4; ++s) {
      float v = red[0][s][dl] + red[1][s][dl] + red[2][s][dl] + red[3][s][dl];
      xo[s*DD + d] = (lens[s] > 0) ? v : empty[d];
    }
  }
}

// ---------------------------------------------------------------------------
// Stage 4a: entity matvecs, float4 streaming, k-split into partials.
// grid (6 col-blocks, 64 k-blocks, 2 matrices) = 768 blocks. HBM-bound.
// ---------------------------------------------------------------------------
__global__ __launch_bounds__(256) void ent_matvec4(
    const float* __restrict__ x,
    const float* __restrict__ Wn, const float* __restrict__ Wg,
    float* __restrict__ pn, float* __restrict__ pg)
{
  const float* W = blockIdx.z ? Wg : Wn;
  float* p = blockIdx.z ? pg : pn;
  __shared__ float xs[96];
  const int db = blockIdx.x;
  const int kb = blockIdx.y;
  const int tid = threadIdx.x;
  if (tid < 96) xs[tid] = x[kb*96 + tid];
  __syncthreads();
  const int col = db*1024 + tid*4;
  float4 a = {0.f,0.f,0.f,0.f};
  const size_t base = (size_t)kb*96*DE + col;
  #pragma unroll 8
  for (int kk = 0; kk < 96; ++kk) {
    const float xv = xs[kk];
    float4 w = *(const float4*)&W[base + (size_t)kk*DE];
    a.x = fmaf(xv, w.x, a.x); a.y = fmaf(xv, w.y, a.y);
    a.z = fmaf(xv, w.z, a.z); a.w = fmaf(xv, w.w, a.w);
  }
  *(float4*)&p[(size_t)kb*DE + col] = a;
}

__global__ __launch_bounds__(256) void ent_reduce(
    const float* __restrict__ pn, const float* __restrict__ pg,
    float* __restrict__ yn, float* __restrict__ yg)
{
  const int o = blockIdx.x*256 + threadIdx.x;
  float sn = 0.f, sg = 0.f;
  for (int kb = 0; kb < 64; ++kb) {
    sn += pn[(size_t)kb*DE + o];
    sg += pg[(size_t)kb*DE + o];
  }
  yn[o] = sn; yg[o] = sg;
}

// ---------------------------------------------------------------------------
// Stage 4b: entity highway + logits + softmax -> out[2].
// ---------------------------------------------------------------------------
__global__ __launch_bounds__(256) void final_kernel(
    const float* __restrict__ x, const float* __restrict__ yn,
    const float* __restrict__ yg, const float* __restrict__ bn,
    const float* __restrict__ bg, const float* __restrict__ Wl,
    const float* __restrict__ bl, float* __restrict__ out)
{
  const int tid = threadIdx.x;
  float a0 = 0.f, a1 = 0.f;
  for (int p = 0; p < DE/256; ++p) {
    int d = p*256 + tid;
    float n  = yn[d] + bn[d];
    float gp = yg[d] + bg[d];
    float h  = fmaxf(n, 0.f);
    float g  = 1.f / (1.f + __expf(-gp));
    float hw = h*g + (1.f - g)*x[d];
    a0 += hw * Wl[d*2 + 0];
    a1 += hw * Wl[d*2 + 1];
  }
  #pragma unroll
  for (int mm = 1; mm < 64; mm <<= 1) {
    a0 += __shfl_xor(a0, mm, 64);
    a1 += __shfl_xor(a1, mm, 64);
  }
  __shared__ float s0[4], s1[4];
  if ((tid & 63) == 0) { s0[tid>>6] = a0; s1[tid>>6] = a1; }
  __syncthreads();
  if (tid == 0) {
    for (int w = 1; w < 4; ++w) { a0 += s0[w]; a1 += s1[w]; }
    float l0 = a0 + bl[0], l1 = a1 + bl[1];
    float m = fmaxf(l0, l1);
    float e0 = __expf(l0 - m), e1 = __expf(l1 - m);
    out[0] = e0 / (e0 + e1);
    out[1] = e1 / (e0 + e1);
  }
}

// ---------------------------------------------------------------------------
extern "C" void kernel_launch(void* const* d_in, const int* in_sizes, int n_in,
                              void* d_out, int out_size, void* d_ws, size_t ws_size,
                              hipStream_t stream) {
  const float* Lemb   = (const float*)d_in[0];
  const float* Remb   = (const float*)d_in[1];
  const float* Wn_tok = (const float*)d_in[2];
  const float* bn_tok = (const float*)d_in[3];
  const float* Wg_tok = (const float*)d_in[4];
  const float* bg_tok = (const float*)d_in[5];
  const float* Wl_tok = (const float*)d_in[6];
  // d_in[7] = b_lin_tok: constant shift, argmax-invariant -> unused
  const float* AEl    = (const float*)d_in[8];
  const float* AEr    = (const float*)d_in[9];
  const float* Wn_ent = (const float*)d_in[10];
  const float* bn_ent = (const float*)d_in[11];
  const float* Wg_ent = (const float*)d_in[12];
  const float* bg_ent = (const float*)d_in[13];
  const float* Wl_ent = (const float*)d_in[14];
  const float* bl_ent = (const float*)d_in[15];
  const float* empty  = (const float*)d_in[16];
  const int*   lensL  = (const int*)d_in[17];
  const int*   lensR  = (const int*)d_in[18];

  char* ws = (char*)d_ws;
  // Sp (12 planes, score stage) overlaps pn/pg (ent stage) -- disjoint in time.
  float* Sp   = (float*)(ws + 0);         // 12*65536 f = 3,145,728 B
  float* pn   = (float*)(ws + 0);         // 64*6144 f = 1,572,864 B
  float* pg   = (float*)(ws + 1572864);   // 64*6144 f
  int*  idxL  = (int*)  (ws + 3145728);   // 256
  int*  idxR  = (int*)  (ws + 3146752);   // 256
  float* x    = (float*)(ws + 3147776);   // 6144 f
  float* yn   = (float*)(ws + 3172352);   // 6144 f
  float* yg   = (float*)(ws + 3196928);   // 6144 f
  float* wSm  = (float*)(ws + 3221504);   // 512 f
  int*  segA  = (int*)  (ws + 3223552);   // 512
  _Float16* WnT = (_Float16*)(ws + 3225600);  // 768*768 f16 (swizzled)
  _Float16* WgT = (_Float16*)(ws + 4405248);  // 768*768 f16 (swizzled)
  _Float16* Lh  = (_Float16*)(ws + 5584896);  // 256*768 f16
  _Float16* Rh  = (_Float16*)(ws + 5978112);  // 256*768 f16

  transpose_cvt<<<dim3(24, 24, 2), 256, 0, stream>>>(Wn_tok, Wg_tok, WnT, WgT);
  cvt_lr<<<dim3(192, 2), 256, 0, stream>>>(Lemb, Remb, Lh, Rh);
  score_mfma<<<dim3(2, 6, 256), 512, 0, stream>>>(
      Lh, Rh, WnT, WgT, bn_tok, bg_tok, Wl_tok, Sp);
  argmax_attr<<<514, 256, 0, stream>>>(
      Sp, idxL, idxR, Lemb, Remb, AEl, AEr, lensL, lensR, wSm, segA);
  attr_reduce<<<dim3(2, 12), 256, 0, stream>>>(
      Lemb, Remb, lensL, lensR, idxL, idxR, wSm, segA, empty, x);
  ent_matvec4<<<dim3(6, 64, 2), 256, 0, stream>>>(x, Wn_ent, Wg_ent, pn, pg);
  ent_reduce<<<24, 256, 0, stream>>>(pn, pg, yn, yg);
  final_kernel<<<1, 256, 0, stream>>>(
      x, yn, yg, bn_ent, bg_ent, Wl_ent, bl_ent, (float*)d_out);
}

// Round 5
// 657.336 us; speedup vs baseline: 1.5489x; 1.4596x over previous
//
#include <hip/hip_runtime.h>
#include <math.h>
#include <stdint.h>

#define DD 768
#define NT 256
#define DE 6144

typedef _Float16 half8 __attribute__((ext_vector_type(8)));
typedef _Float16 half4 __attribute__((ext_vector_type(4)));
typedef short short8 __attribute__((ext_vector_type(8)));
typedef float floatx4 __attribute__((ext_vector_type(4)));

__device__ __forceinline__ void async_ld16(const void* g, void* l) {
  __builtin_amdgcn_global_load_lds(
      (const __attribute__((address_space(1))) unsigned int*)g,
      (__attribute__((address_space(3))) unsigned int*)l, 16, 0, 0);
}

// ---------------------------------------------------------------------------
// Prep A: WT[d][k] = (f16)W[k][d], XOR-swizzled within each 64-f16 chunk:
// 16B-group g of row d lives at group g^(d&7), so lane-contiguous
// global_load_lds lands a bank-balanced image in LDS.
// ---------------------------------------------------------------------------
__global__ __launch_bounds__(256) void transpose_cvt(
    const float* __restrict__ Wn, const float* __restrict__ Wg,
    _Float16* __restrict__ WnT, _Float16* __restrict__ WgT)
{
  const float* W = blockIdx.z ? Wg : Wn;
  _Float16* WT = blockIdx.z ? WgT : WnT;
  __shared__ float tile[32][33];
  const int tx = threadIdx.x & 31, ty = threadIdx.x >> 5;
  const int d0 = blockIdx.x * 32, k0 = blockIdx.y * 32;
  #pragma unroll
  for (int p = 0; p < 4; ++p)
    tile[ty + p*8][tx] = W[(size_t)(k0 + ty + p*8)*DD + d0 + tx];
  __syncthreads();
  #pragma unroll
  for (int p = 0; p < 4; ++p) {
    const int d = d0 + ty + p*8;
    const int k = k0 + tx;
    const int idx = d*DD + (k & ~63) + ((((k >> 3) & 7) ^ (d & 7)) << 3) + (k & 7);
    WT[idx] = (_Float16)tile[tx][ty + p*8];
  }
}

// ---------------------------------------------------------------------------
// Prep B: fp16 copies of the embeddings (A-operand source for score_mfma).
// ---------------------------------------------------------------------------
__global__ __launch_bounds__(256) void cvt_lr(
    const float* __restrict__ L, const float* __restrict__ R,
    _Float16* __restrict__ Lh, _Float16* __restrict__ Rh)
{
  const float* src = blockIdx.y ? R : L;
  _Float16* dst = blockIdx.y ? Rh : Lh;
  const int o = blockIdx.x*1024 + threadIdx.x*4;
  float4 v = *(const float4*)&src[o];
  half4 h; h[0] = (_Float16)v.x; h[1] = (_Float16)v.y;
  h[2] = (_Float16)v.z; h[3] = (_Float16)v.w;
  *(half4*)&dst[o] = h;
}

// ---------------------------------------------------------------------------
// Stage 1 v6: stage-early + ONE sync per K-step, 8 waves.
// Ladder so far: r0 2-barrier 128-tile = 220us (MfmaUtil 31). r1 dbuf at 4
// waves/CU = 321us (1 wave/SIMD, no overlap). r2 4-phase with per-phase
// FULL drains = 223us (drain-0 kills phase-split, cf. m218). r3/r4
// A-direct-from-global = spill / latency-exposed at 1 block/CU.
// Synthesis: r2's geometry (512 thr = 8 waves, tile 256j x 128d, BK=64,
// A/Bn/Bg all double-buffered = 128 KB LDS) + r1's schedule (issue DMA-B and
// Rh register-loads for step t+1 FIRST, then the full 64-MFMA compute, then
// A-build from the prefetched regs, then ONE __syncthreads). The sync's
// vmcnt(0) drain is near-free: its targets were issued ~2K cycles earlier;
// Rh L2 latency hides under the MFMA cluster; per-wave drain + barrier
// gives cross-wave DMA visibility with no hand-rolled waitcnt (safe).
// Accumulation per acc element: k ascending, unchanged from r0 -> Sp
// bit-identical -> argmax identical -> absmax 0.
// ---------------------------------------------------------------------------
__global__ __launch_bounds__(512, 1) void score_mfma(
    const _Float16* __restrict__ Lh, const _Float16* __restrict__ Rh,
    const _Float16* __restrict__ WnT, const _Float16* __restrict__ WgT,
    const float* __restrict__ bn, const float* __restrict__ bg,
    const float* __restrict__ Wl, float* __restrict__ Sp)
{
  const int dbase = blockIdx.x * 128;   // 6 d-blocks
  const int i     = blockIdx.y;         // 256 i
  const int tid   = threadIdx.x;

  __shared__ _Float16 As [2][256*64];   // 2 x 32 KB
  __shared__ _Float16 Bns[2][128*64];   // 2 x 16 KB
  __shared__ _Float16 Bgs[2][128*64];   // 2 x 16 KB

  floatx4 accn[4][4] = {};
  floatx4 accg[4][4] = {};

  const int kg = tid & 7;     // 16B group within 64-f16 row (A staging)
  const int rl = tid >> 3;    // 0..63 base row for A build

  const int lane = tid & 63;
  const int wid  = tid >> 6;            // 0..7
  const int wj = (wid & 3) * 64;        // 4 waves across j (full 256)
  const int wd = (wid >> 2) * 64;       // 2 waves across d
  const int m = lane & 15;
  const int q = lane >> 4;
  const int gq8 = ((q ^ (m & 7)) << 3); // swizzled fragment k-offset base

  const int drow = lane >> 3;   // DMA: 8 rows/inst
  const int dseg = lane & 7;

  int arow[4], brow[4];
  #pragma unroll
  for (int t4 = 0; t4 < 4; ++t4) {
    arow[t4] = (wj + t4*16 + m) * 64;
    brow[t4] = (wd + t4*16 + m) * 64;
  }

  auto stageB = [&](int k0, int c) {
    #pragma unroll
    for (int tt = 0; tt < 2; ++tt) {
      const int brow0 = wid*16 + tt*8;
      async_ld16(&WnT[(size_t)(dbase + brow0 + drow)*DD + k0 + dseg*8],
                 &Bns[c][brow0*64]);
      async_ld16(&WgT[(size_t)(dbase + brow0 + drow)*DD + k0 + dseg*8],
                 &Bgs[c][brow0*64]);
    }
  };

  // ---- prologue: stage K-step 0 into buffer 0 (A inline-built)
  stageB(0, 0);
  {
    half8 lh0 = *(const half8*)&Lh[i*DD + kg*8];
    #pragma unroll
    for (int rep = 0; rep < 4; ++rep) {
      const int row = rl + rep*64;
      half8 rv0 = *(const half8*)&Rh[(size_t)row*DD + kg*8];
      half8 dv8 = lh0 - rv0;
      short8 sb; __builtin_memcpy(&sb, &dv8, 16);
      sb &= (short)0x7FFF;
      *(short8*)&As[0][row*64 + ((kg ^ (row & 7)) << 3)] = sb;
    }
  }
  __syncthreads();

  // ---- main loop: 12 K-steps, one __syncthreads each
  for (int t = 0; t < 12; ++t) {
    const int cur = t & 1;
    const bool st = (t < 11);
    const int k0n = (t + 1) * 64;

    // ---- stage-issue for t+1: DMA B into freed buffer + Rh/Lh to regs.
    half8 rv[4], lh;
    if (st) {
      stageB(k0n, cur ^ 1);
      __builtin_amdgcn_sched_barrier(0);   // pin DMA issue before reg loads
      lh = *(const half8*)&Lh[i*DD + k0n + kg*8];
      #pragma unroll
      for (int rep = 0; rep < 4; ++rep)
        rv[rep] = *(const half8*)&Rh[(size_t)(rl + rep*64)*DD + k0n + kg*8];
      __builtin_amdgcn_sched_barrier(0);   // pin all issues before compute
    }

    // ---- compute(cur): 24 ds_read_b128 + 64 MFMA per wave
    half8 af[4][2];
    #pragma unroll
    for (int tj = 0; tj < 4; ++tj)
      #pragma unroll
      for (int kk = 0; kk < 2; ++kk)
        af[tj][kk] = *(const half8*)&As[cur][arow[tj] + ((kk*32) ^ gq8)];
    __builtin_amdgcn_s_setprio(1);
    #pragma unroll
    for (int td = 0; td < 4; ++td) {
      half8 bn_[2], bg_[2];
      #pragma unroll
      for (int kk = 0; kk < 2; ++kk) {
        bn_[kk] = *(const half8*)&Bns[cur][brow[td] + ((kk*32) ^ gq8)];
        bg_[kk] = *(const half8*)&Bgs[cur][brow[td] + ((kk*32) ^ gq8)];
      }
      #pragma unroll
      for (int kk = 0; kk < 2; ++kk)
        #pragma unroll
        for (int tj = 0; tj < 4; ++tj) {
          accn[tj][td] = __builtin_amdgcn_mfma_f32_16x16x32_f16(
              af[tj][kk], bn_[kk], accn[tj][td], 0, 0, 0);
          accg[tj][td] = __builtin_amdgcn_mfma_f32_16x16x32_f16(
              af[tj][kk], bg_[kk], accg[tj][td], 0, 0, 0);
        }
    }
    __builtin_amdgcn_s_setprio(0);

    // ---- A-build(t+1) from prefetched regs (Rh latency hid under MFMA)
    if (st) {
      #pragma unroll
      for (int rep = 0; rep < 4; ++rep) {
        const int row = rl + rep*64;
        half8 dv8 = lh - rv[rep];
        short8 sb; __builtin_memcpy(&sb, &dv8, 16);
        sb &= (short)0x7FFF;
        *(short8*)&As[cur ^ 1][row*64 + ((kg ^ (row & 7)) << 3)] = sb;
      }
    }
    __syncthreads();   // drains DMA(t+1) (issued ~2K cyc ago, near-free)
                       // + A ds_writes; frees buf cur for step t+2
  }

  // ---- epilogue: highway + Wl contraction; C layout col=lane&15, row=q*4+r
  float bnv[4], bgv[4], wlv[4], lv[4];
  int dv[4];
  #pragma unroll
  for (int td = 0; td < 4; ++td) {
    const int d = dbase + wd + td*16 + m;
    dv[td] = d; bnv[td] = bn[d]; bgv[td] = bg[d]; wlv[td] = Wl[d];
    lv[td] = (float)Lh[i*DD + d];
  }
  const int jb = wj;
  const int plane = blockIdx.x * 2 + (wid >> 2);   // 12 planes
  float* Sout = Sp + (size_t)plane * NT * NT + (size_t)i * NT;
  #pragma unroll
  for (int tj = 0; tj < 4; ++tj) {
    #pragma unroll
    for (int r = 0; r < 4; ++r) {
      const int j = jb + tj*16 + q*4 + r;
      float sc = 0.f;
      #pragma unroll
      for (int td = 0; td < 4; ++td) {
        const float nv = accn[tj][td][r] + bnv[td];
        const float gp = accg[tj][td][r] + bgv[td];
        const float g  = 1.f / (1.f + __expf(-gp));
        const float c  = fabsf(lv[td] - (float)Rh[(size_t)j*DD + dv[td]]);
        sc += (fmaxf(nv, 0.f)*g + (1.f - g)*c) * wlv[td];
      }
      sc += __shfl_xor(sc, 1, 16);
      sc += __shfl_xor(sc, 2, 16);
      sc += __shfl_xor(sc, 4, 16);
      sc += __shfl_xor(sc, 8, 16);
      if (m == 0) Sout[j] = sc;
    }
  }
}

// ---------------------------------------------------------------------------
// Stage 2 (fused): blocks 0..511 -> argmax over rows/cols of sum-of-planes S;
// blocks 512/513 -> per-token attribute scores + segment softmax weights.
// ---------------------------------------------------------------------------
__global__ __launch_bounds__(256) void argmax_attr(
    const float* __restrict__ Sp,
    int* __restrict__ idxL, int* __restrict__ idxR,
    const float* __restrict__ Lemb, const float* __restrict__ Remb,
    const float* __restrict__ AEl, const float* __restrict__ AEr,
    const int* __restrict__ lensL, const int* __restrict__ lensR,
    float* __restrict__ wS, int* __restrict__ segA)
{
  const int b = blockIdx.x;
  const int t = threadIdx.x;

  if (b < 2*NT) {
    // ---- argmax path
    const size_t off = (b < NT) ? ((size_t)b*NT + t) : ((size_t)t*NT + (b - NT));
    float v = 0.f;
    #pragma unroll
    for (int p = 0; p < 12; ++p) v += Sp[(size_t)p*NT*NT + off];
    int idx = t;
    #pragma unroll
    for (int mm = 1; mm < 64; mm <<= 1) {
      float ov = __shfl_xor(v, mm, 64);
      int   oi = __shfl_xor(idx, mm, 64);
      if (ov > v || (ov == v && oi < idx)) { v = ov; idx = oi; }
    }
    __shared__ float sv[4]; __shared__ int si[4];
    if ((t & 63) == 0) { sv[t>>6] = v; si[t>>6] = idx; }
    __syncthreads();
    if (t == 0) {
      #pragma unroll
      for (int w = 1; w < 4; ++w)
        if (sv[w] > v || (sv[w] == v && si[w] < idx)) { v = sv[w]; idx = si[w]; }
      if (b < NT) idxL[b] = idx; else idxR[b - NT] = idx;
    }
    return;
  }

  // ---- attr_score path (b = 512 -> left, 513 -> right)
  const int side = b - 2*NT;
  const float* tok = side ? Remb : Lemb;
  const float* AE  = side ? AEr  : AEl;
  const int* lens  = side ? lensR : lensL;
  const int c0 = lens[0], c1 = c0 + lens[1], c2 = c1 + lens[2];
  const int seg = (t < c0) ? 0 : (t < c1) ? 1 : (t < c2) ? 2 : 3;
  float s = 0.f;
  const float4* tr = (const float4*)&tok[(size_t)t*DD];
  const float4* ar = (const float4*)&AE[(size_t)seg*DD];
  for (int k = 0; k < DD/4; ++k) {
    float4 a = tr[k], bb = ar[k];
    s += a.x*bb.x + a.y*bb.y + a.z*bb.z + a.w*bb.w;
  }
  __shared__ float scS[NT]; __shared__ int segS[NT];
  __shared__ float mS[4], zS[4];
  scS[t] = s; segS[t] = seg;
  __syncthreads();
  if (t < 4) {
    float mx = -INFINITY;
    for (int u = 0; u < NT; ++u) if (segS[u] == t) mx = fmaxf(mx, scS[u]);
    mS[t] = mx;
    float z = 0.f;
    for (int u = 0; u < NT; ++u) if (segS[u] == t) z += __expf(scS[u] - mx);
    zS[t] = z;
  }
  __syncthreads();
  wS[side*NT + t] = __expf(s - mS[seg]) / zS[seg];
  segA[side*NT + t] = seg;
}

// ---------------------------------------------------------------------------
// Stage 3: weighted segment reduction of cmp rows, d-parallel (2x12 blocks).
// cmp recomputed in EXACT fp32 from the original embeddings.
// ---------------------------------------------------------------------------
__global__ __launch_bounds__(256) void attr_reduce(
    const float* __restrict__ Lemb, const float* __restrict__ Remb,
    const int* __restrict__ lensL, const int* __restrict__ lensR,
    const int* __restrict__ idxL, const int* __restrict__ idxR,
    const float* __restrict__ wS, const int* __restrict__ segA,
    const float* __restrict__ empty, float* __restrict__ x)
{
  const int side = blockIdx.x;
  const float* tok = side ? Remb : Lemb;
  const float* oth = side ? Lemb : Remb;
  const int* lens  = side ? lensR : lensL;
  const int* idx   = side ? idxR  : idxL;
  const float* w   = wS + side*NT;
  const int* sg    = segA + side*NT;
  float* xo = x + side*4*DD;
  const int t = threadIdx.x;
  const int dl = t & 63, uq = t >> 6;
  const int d = blockIdx.y*64 + dl;
  float a0 = 0.f, a1 = 0.f, a2 = 0.f, a3 = 0.f;
  for (int u = uq*64; u < uq*64 + 64; ++u) {
    const float c = fabsf(tok[(size_t)u*DD + d] - oth[(size_t)idx[u]*DD + d]);
    const float wc = w[u] * c;
    const int s = sg[u];
    a0 += (s == 0) ? wc : 0.f;
    a1 += (s == 1) ? wc : 0.f;
    a2 += (s == 2) ? wc : 0.f;
    a3 += (s == 3) ? wc : 0.f;
  }
  __shared__ float red[4][4][64];
  red[uq][0][dl] = a0; red[uq][1][dl] = a1;
  red[uq][2][dl] = a2; red[uq][3][dl] = a3;
  __syncthreads();
  if (uq == 0) {
    #pragma unroll
    for (int s = 0; s < 4; ++s) {
      float v = red[0][s][dl] + red[1][s][dl] + red[2][s][dl] + red[3][s][dl];
      xo[s*DD + d] = (lens[s] > 0) ? v : empty[d];
    }
  }
}

// ---------------------------------------------------------------------------
// Stage 4a: entity matvecs, float4 streaming, k-split into partials.
// grid (6 col-blocks, 64 k-blocks, 2 matrices) = 768 blocks. HBM-bound.
// ---------------------------------------------------------------------------
__global__ __launch_bounds__(256) void ent_matvec4(
    const float* __restrict__ x,
    const float* __restrict__ Wn, const float* __restrict__ Wg,
    float* __restrict__ pn, float* __restrict__ pg)
{
  const float* W = blockIdx.z ? Wg : Wn;
  float* p = blockIdx.z ? pg : pn;
  __shared__ float xs[96];
  const int db = blockIdx.x;
  const int kb = blockIdx.y;
  const int tid = threadIdx.x;
  if (tid < 96) xs[tid] = x[kb*96 + tid];
  __syncthreads();
  const int col = db*1024 + tid*4;
  float4 a = {0.f,0.f,0.f,0.f};
  const size_t base = (size_t)kb*96*DE + col;
  #pragma unroll 8
  for (int kk = 0; kk < 96; ++kk) {
    const float xv = xs[kk];
    float4 w = *(const float4*)&W[base + (size_t)kk*DE];
    a.x = fmaf(xv, w.x, a.x); a.y = fmaf(xv, w.y, a.y);
    a.z = fmaf(xv, w.z, a.z); a.w = fmaf(xv, w.w, a.w);
  }
  *(float4*)&p[(size_t)kb*DE + col] = a;
}

__global__ __launch_bounds__(256) void ent_reduce(
    const float* __restrict__ pn, const float* __restrict__ pg,
    float* __restrict__ yn, float* __restrict__ yg)
{
  const int o = blockIdx.x*256 + threadIdx.x;
  float sn = 0.f, sg = 0.f;
  for (int kb = 0; kb < 64; ++kb) {
    sn += pn[(size_t)kb*DE + o];
    sg += pg[(size_t)kb*DE + o];
  }
  yn[o] = sn; yg[o] = sg;
}

// ---------------------------------------------------------------------------
// Stage 4b: entity highway + logits + softmax -> out[2].
// ---------------------------------------------------------------------------
__global__ __launch_bounds__(256) void final_kernel(
    const float* __restrict__ x, const float* __restrict__ yn,
    const float* __restrict__ yg, const float* __restrict__ bn,
    const float* __restrict__ bg, const float* __restrict__ Wl,
    const float* __restrict__ bl, float* __restrict__ out)
{
  const int tid = threadIdx.x;
  float a0 = 0.f, a1 = 0.f;
  for (int p = 0; p < DE/256; ++p) {
    int d = p*256 + tid;
    float n  = yn[d] + bn[d];
    float gp = yg[d] + bg[d];
    float h  = fmaxf(n, 0.f);
    float g  = 1.f / (1.f + __expf(-gp));
    float hw = h*g + (1.f - g)*x[d];
    a0 += hw * Wl[d*2 + 0];
    a1 += hw * Wl[d*2 + 1];
  }
  #pragma unroll
  for (int mm = 1; mm < 64; mm <<= 1) {
    a0 += __shfl_xor(a0, mm, 64);
    a1 += __shfl_xor(a1, mm, 64);
  }
  __shared__ float s0[4], s1[4];
  if ((tid & 63) == 0) { s0[tid>>6] = a0; s1[tid>>6] = a1; }
  __syncthreads();
  if (tid == 0) {
    for (int w = 1; w < 4; ++w) { a0 += s0[w]; a1 += s1[w]; }
    float l0 = a0 + bl[0], l1 = a1 + bl[1];
    float m = fmaxf(l0, l1);
    float e0 = __expf(l0 - m), e1 = __expf(l1 - m);
    out[0] = e0 / (e0 + e1);
    out[1] = e1 / (e0 + e1);
  }
}

// ---------------------------------------------------------------------------
extern "C" void kernel_launch(void* const* d_in, const int* in_sizes, int n_in,
                              void* d_out, int out_size, void* d_ws, size_t ws_size,
                              hipStream_t stream) {
  const float* Lemb   = (const float*)d_in[0];
  const float* Remb   = (const float*)d_in[1];
  const float* Wn_tok = (const float*)d_in[2];
  const float* bn_tok = (const float*)d_in[3];
  const float* Wg_tok = (const float*)d_in[4];
  const float* bg_tok = (const float*)d_in[5];
  const float* Wl_tok = (const float*)d_in[6];
  // d_in[7] = b_lin_tok: constant shift, argmax-invariant -> unused
  const float* AEl    = (const float*)d_in[8];
  const float* AEr    = (const float*)d_in[9];
  const float* Wn_ent = (const float*)d_in[10];
  const float* bn_ent = (const float*)d_in[11];
  const float* Wg_ent = (const float*)d_in[12];
  const float* bg_ent = (const float*)d_in[13];
  const float* Wl_ent = (const float*)d_in[14];
  const float* bl_ent = (const float*)d_in[15];
  const float* empty  = (const float*)d_in[16];
  const int*   lensL  = (const int*)d_in[17];
  const int*   lensR  = (const int*)d_in[18];

  char* ws = (char*)d_ws;
  // Sp (12 planes, score stage) overlaps pn/pg (ent stage) -- disjoint in time.
  float* Sp   = (float*)(ws + 0);         // 12*65536 f = 3,145,728 B
  float* pn   = (float*)(ws + 0);         // 64*6144 f = 1,572,864 B
  float* pg   = (float*)(ws + 1572864);   // 64*6144 f
  int*  idxL  = (int*)  (ws + 3145728);   // 256
  int*  idxR  = (int*)  (ws + 3146752);   // 256
  float* x    = (float*)(ws + 3147776);   // 6144 f
  float* yn   = (float*)(ws + 3172352);   // 6144 f
  float* yg   = (float*)(ws + 3196928);   // 6144 f
  float* wSm  = (float*)(ws + 3221504);   // 512 f
  int*  segA  = (int*)  (ws + 3223552);   // 512
  _Float16* WnT = (_Float16*)(ws + 3225600);  // 768*768 f16 (swizzled)
  _Float16* WgT = (_Float16*)(ws + 4405248);  // 768*768 f16 (swizzled)
  _Float16* Lh  = (_Float16*)(ws + 5584896);  // 256*768 f16
  _Float16* Rh  = (_Float16*)(ws + 5978112);  // 256*768 f16

  transpose_cvt<<<dim3(24, 24, 2), 256, 0, stream>>>(Wn_tok, Wg_tok, WnT, WgT);
  cvt_lr<<<dim3(192, 2), 256, 0, stream>>>(Lemb, Remb, Lh, Rh);
  score_mfma<<<dim3(6, 256), 512, 0, stream>>>(
      Lh, Rh, WnT, WgT, bn_tok, bg_tok, Wl_tok, Sp);
  argmax_attr<<<514, 256, 0, stream>>>(
      Sp, idxL, idxR, Lemb, Remb, AEl, AEr, lensL, lensR, wSm, segA);
  attr_reduce<<<dim3(2, 12), 256, 0, stream>>>(
      Lemb, Remb, lensL, lensR, idxL, idxR, wSm, segA, empty, x);
  ent_matvec4<<<dim3(6, 64, 2), 256, 0, stream>>>(x, Wn_ent, Wg_ent, pn, pg);
  ent_reduce<<<24, 256, 0, stream>>>(pn, pg, yn, yg);
  final_kernel<<<1, 256, 0, stream>>>(
      x, yn, yg, bn_ent, bg_ent, Wl_ent, bl_ent, (float*)d_out);
}